// Round 7
// baseline (578.882 us; speedup 1.0000x reference)
//
#include <hip/hip_runtime.h>

// Soft-circuit FP32 scale-by-2^k, reduced to integer bit ops.
// Row layout (element e <-> bit e of packed word):
//   bit 0      = sign
//   bits 1..8  = exponent, element 1 = MSB
//   bits 9..31 = mantissa, element 9 = MSB
//
// v7: v6's verified per-element pipeline (8 lanes/row, low-quad DPP gather,
// ballot k==0 test, nontemporal input loads) in the CANONICAL grid-stride
// shape of the two kernels measured at the streaming ceiling on this chip
// (rocclr fillBuffer: 6.5 TB/s, float4 copy: 6.29 TB/s -- both loop with
// stride = total-threads, one vector per iteration, no unroll batching):
//  - 2048 blocks x 256 threads, stride T = 524288 float4s
//  - one float4 per iteration; T % 8 == 0 so row-position g is loop-invariant
//  - ~16 VGPR -> full occupancy; wave launch/kernarg cost amortized 32x
// Memory-bound: 804 MB logical traffic; HBM-compulsory 512 MiB/dispatch.

// native vector type for __builtin_nontemporal_load (HIP_vector_type rejected)
typedef float fvec4 __attribute__((ext_vector_type(4)));

__device__ __forceinline__ unsigned rev8(unsigned v) {
    // reverse the low 8 bits
    return __builtin_bitreverse32(v) >> 24;
}

__device__ __forceinline__ unsigned nib4(const fvec4 v) {
    return (unsigned)(v.x != 0.0f)
         | ((unsigned)(v.y != 0.0f) << 1)
         | ((unsigned)(v.z != 0.0f) << 2)
         | ((unsigned)(v.w != 0.0f) << 3);
}

// OR across the 4 lanes of a quad using DPP quad_perm (VALU pipe only).
__device__ __forceinline__ unsigned quad_or(unsigned w) {
    // quad_perm [1,0,3,2] = 0xB1  (lane ^ 1)
    w |= (unsigned)__builtin_amdgcn_update_dpp(0, (int)w, 0xB1, 0xF, 0xF, true);
    // quad_perm [2,3,0,1] = 0x4E  (lane ^ 2)
    w |= (unsigned)__builtin_amdgcn_update_dpp(0, (int)w, 0x4E, 0xF, 0xF, true);
    return w;
}

__global__ __launch_bounds__(256) void spike_scale_kernel(
        const float4* __restrict__ x4,
        const float4* __restrict__ k4,
        float4* __restrict__ o4,
        int nvec) {
    const int T   = (int)(gridDim.x * 256u);
    const int tid = (int)(blockIdx.x * 256u + threadIdx.x);

    // T % 8 == 0 and tid % 8 == threadIdx.x % 8 -> all loop-invariant:
    const unsigned g     = (unsigned)(tid & 7);       // position within the row
    const unsigned sh    = g * 4u;
    const unsigned kmask = (g == 0u) ? 0xEu : 0xFu;   // drop k sign bit in lane 0
    const unsigned me    = (0x1FEu >> sh) & 0xFu;     // my exponent-bit mask
    const unsigned lane  = (unsigned)(threadIdx.x & 63u);

    const fvec4* xv = (const fvec4*)x4;
    const fvec4* kv = (const fvec4*)k4;

    for (int i = tid; i < nvec; i += T) {
        fvec4 vx = __builtin_nontemporal_load(&xv[i]);
        fvec4 vk = __builtin_nontemporal_load(&kv[i]);

        unsigned nibx = nib4(vx);
        unsigned nibk = nib4(vk);

        // k == 0 test (ignoring k's sign bit): one ballot over the 8-lane group
        unsigned long long ball = __ballot((nibk & kmask) != 0u);
        bool kz = (((unsigned)(ball >> (lane & 56u)) & 0xFFu) == 0u);

        // gather row bits 0..15 of x and k across the low quad
        unsigned w = quad_or((nibx << ((g & 3u) * 4u))
                           | (nibk << (16u + (g & 3u) * 4u)));
        unsigned xlo = w & 0xFFFFu;     // x bits 0..15
        unsigned klo = w >> 16;         // k bits 0..15

        // identical arithmetic to the harness-verified v1/v3/v6
        unsigned ek   = rev8((klo >> 1) & 0xFFu);                                  // exponent of k
        unsigned val  = 0x80u | (__builtin_bitreverse32((klo >> 9) & 0x7Fu) >> 25);// 1.m (8-bit)
        unsigned s    = (ek - 127u) & 7u;
        unsigned kabs = val >> (7u - s);
        unsigned kfin = (klo & 1u) ? ((0u - kabs) & 0xFFu) : kabs;
        unsigned ex   = rev8((xlo >> 1) & 0xFFu);
        unsigned er   = rev8((ex + kfin) & 0xFFu) << 1;   // new exponent, bits 1..8

        // per-lane recombine: which of my 4 bits are exponent bits?
        unsigned scaled_n = ((er >> sh) & me) | (nibx & (me ^ 0xFu));
        unsigned res      = kz ? nibx : scaled_n;

        float4 out;
        out.x = (float)(res & 1u);
        out.y = (float)((res >> 1) & 1u);
        out.z = (float)((res >> 2) & 1u);
        out.w = (float)((res >> 3) & 1u);
        o4[i] = out;
    }
}

extern "C" void kernel_launch(void* const* d_in, const int* in_sizes, int n_in,
                              void* d_out, int out_size, void* d_ws, size_t ws_size,
                              hipStream_t stream) {
    const float4* x4 = (const float4*)d_in[0];
    const float4* k4 = (const float4*)d_in[1];
    float4* o4 = (float4*)d_out;

    int n_elems = in_sizes[0];          // N * 32 floats
    int nvec    = n_elems / 4;          // float4 vectors
    int blocks  = (nvec + 255) / 256;
    if (blocks > 2048) blocks = 2048;   // grid-stride, fill/copy-shaped

    spike_scale_kernel<<<blocks, 256, 0, stream>>>(x4, k4, o4, nvec);
}

// Round 8
// 549.543 us; speedup vs baseline: 1.0534x; 1.0534x over previous
//
#include <hip/hip_runtime.h>

// Soft-circuit FP32 scale-by-2^k, reduced to integer bit ops.
// Row layout (element e <-> bit e of packed word):
//   bit 0      = sign
//   bits 1..8  = exponent, element 1 = MSB
//   bits 9..31 = mantissa, element 9 = MSB
//
// v8: v6's exact structure (one-shot, 1 float4/thread, 8 lanes/row, DPP
// low-quad gather, ballot k==0 test, NONTEMPORAL input loads -- the best
// harness-verified version, per-dispatch <163 us), with ONE variable added:
// NONTEMPORAL stores. v2's nt-store +12% WRITE_SIZE penalty was measured on
// the quad layout (partial-line 64B fragments, stride 128); here every wave
// store covers 16 complete contiguous 64B lines, so nt cannot fragment --
// it only removes 268 MB of L3 write-allocate churn, leaving L3 to reads.

// native vector type for nontemporal builtins (HIP_vector_type is rejected)
typedef float fvec4 __attribute__((ext_vector_type(4)));

__device__ __forceinline__ unsigned rev8(unsigned v) {
    // reverse the low 8 bits
    return __builtin_bitreverse32(v) >> 24;
}

__device__ __forceinline__ unsigned nib4(const fvec4 v) {
    return (unsigned)(v.x != 0.0f)
         | ((unsigned)(v.y != 0.0f) << 1)
         | ((unsigned)(v.z != 0.0f) << 2)
         | ((unsigned)(v.w != 0.0f) << 3);
}

// OR across the 4 lanes of a quad using DPP quad_perm (VALU pipe only).
__device__ __forceinline__ unsigned quad_or(unsigned w) {
    // quad_perm [1,0,3,2] = 0xB1  (lane ^ 1)
    w |= (unsigned)__builtin_amdgcn_update_dpp(0, (int)w, 0xB1, 0xF, 0xF, true);
    // quad_perm [2,3,0,1] = 0x4E  (lane ^ 2)
    w |= (unsigned)__builtin_amdgcn_update_dpp(0, (int)w, 0x4E, 0xF, 0xF, true);
    return w;
}

__global__ __launch_bounds__(256) void spike_scale_kernel(
        const float4* __restrict__ x4,
        const float4* __restrict__ k4,
        float4* __restrict__ o4,
        int nvec) {
    int idx = blockIdx.x * 256 + threadIdx.x;
    if (idx >= nvec) return;

    const fvec4* xv = (const fvec4*)x4;
    const fvec4* kv = (const fvec4*)k4;
    fvec4 vx = __builtin_nontemporal_load(&xv[idx]);
    fvec4 vk = __builtin_nontemporal_load(&kv[idx]);

    unsigned g  = (unsigned)(idx & 7);   // this thread's 4 elems within the row
    unsigned sh = g * 4u;

    unsigned nibx = nib4(vx);
    unsigned nibk = nib4(vk);

    // ---- k == 0 test (ignoring k's sign bit): one ballot, no chain ----
    unsigned kmask = (g == 0u) ? 0xEu : 0xFu;       // drop sign bit in lane 0
    unsigned long long ball = __ballot((nibk & kmask) != 0u);
    unsigned lane = (unsigned)(threadIdx.x & 63u);
    bool kz = (((unsigned)(ball >> (lane & 56u)) & 0xFFu) == 0u);

    // ---- gather row bits 0..15 of x and k across the low quad ----
    // lanes g>=4 compute garbage here, but they never use it (me == 0 below)
    unsigned w = quad_or((nibx << ((g & 3u) * 4u))
                       | (nibk << (16u + (g & 3u) * 4u)));
    unsigned xlo = w & 0xFFFFu;     // x bits 0..15 (sign + exponent + m0..m6)
    unsigned klo = w >> 16;         // k bits 0..15

    // ---- identical arithmetic to the harness-verified v1/v3/v6 ----
    unsigned ek   = rev8((klo >> 1) & 0xFFu);                                  // exponent of k
    unsigned val  = 0x80u | (__builtin_bitreverse32((klo >> 9) & 0x7Fu) >> 25);// 1.m (8-bit)
    unsigned s    = (ek - 127u) & 7u;
    unsigned kabs = val >> (7u - s);
    unsigned kfin = (klo & 1u) ? ((0u - kabs) & 0xFFu) : kabs;
    unsigned ex   = rev8((xlo >> 1) & 0xFFu);
    unsigned er   = rev8((ex + kfin) & 0xFFu) << 1;   // new exponent, bits 1..8

    // per-lane recombine: which of my 4 bits are exponent bits?
    unsigned me       = (0x1FEu >> sh) & 0xFu;        // 0xE, 0xF, 0x1, 0, 0, ...
    unsigned scaled_n = ((er >> sh) & me) | (nibx & (me ^ 0xFu));
    unsigned res      = kz ? nibx : scaled_n;

    fvec4 out;
    out.x = (float)(res & 1u);
    out.y = (float)((res >> 1) & 1u);
    out.z = (float)((res >> 2) & 1u);
    out.w = (float)((res >> 3) & 1u);
    fvec4* ov = (fvec4*)o4;
    __builtin_nontemporal_store(out, &ov[idx]);
}

extern "C" void kernel_launch(void* const* d_in, const int* in_sizes, int n_in,
                              void* d_out, int out_size, void* d_ws, size_t ws_size,
                              hipStream_t stream) {
    const float4* x4 = (const float4*)d_in[0];
    const float4* k4 = (const float4*)d_in[1];
    float4* o4 = (float4*)d_out;

    int n_elems = in_sizes[0];          // N * 32 floats
    int nvec    = n_elems / 4;          // float4 vectors
    int blocks  = (nvec + 255) / 256;

    spike_scale_kernel<<<blocks, 256, 0, stream>>>(x4, k4, o4, nvec);
}